// Round 1
// baseline (1574.246 us; speedup 1.0000x reference)
//
#include <hip/hip_runtime.h>
#include <hip/hip_bf16.h>
#include <math.h>

#define TB 4
#define TT 4096
#define HH 2048
#define DD 256
#define NN 32768
#define HQ 512
#define MM (TB*TT)

typedef __attribute__((ext_vector_type(8))) short bf16x8;
typedef __attribute__((ext_vector_type(4))) float f32x4;

__device__ inline unsigned short f2bf(float x){
  __hip_bfloat16 h = __float2bfloat16(x);
  return *reinterpret_cast<unsigned short*>(&h);
}

__device__ inline bf16x8 as_bf16x8(uint4 u){ bf16x8 r; __builtin_memcpy(&r,&u,16); return r; }

// K1: hidden_mean over batch: hm[t,h] = mean_b hidden[b,t,h]
__global__ __launch_bounds__(256) void k_mean_b(const float* __restrict__ h, float* __restrict__ hm){
  const int i = blockIdx.x*256 + threadIdx.x;      // float4 index, T*H/4 total
  const int TH4 = TT*HH/4;
  const float4* p = (const float4*)h;
  float4 a = p[i], b = p[i+TH4], c = p[i+2*TH4], d = p[i+3*TH4];
  float4 o;
  o.x = 0.25f*(a.x+b.x+c.x+d.x);
  o.y = 0.25f*(a.y+b.y+c.y+d.y);
  o.z = 0.25f*(a.z+b.z+c.z+d.z);
  o.w = 0.25f*(a.w+b.w+c.w+d.w);
  ((float4*)hm)[i] = o;
}

// K2: obs_mean = hm @ W_obs^T   [4096,2048] x [256,2048]^T -> [4096,256]
__global__ __launch_bounds__(256) void k_gemm_obs(const float* __restrict__ A,
    const float* __restrict__ Bw, float* __restrict__ C){
  __shared__ float As[16][68];
  __shared__ float Bs[16][68];
  const int tid = threadIdx.x;
  const int tx = tid & 15, ty = tid >> 4;
  const int m0 = blockIdx.x*64, n0 = blockIdx.y*64;
  float acc[4][4] = {};
  const int kl = tid & 15, rl = tid >> 4;
  for (int k0 = 0; k0 < HH; k0 += 16){
    #pragma unroll
    for (int i = 0; i < 4; i++){
      As[kl][rl + i*16] = A[(size_t)(m0 + rl + i*16)*HH + k0 + kl];
      Bs[kl][rl + i*16] = Bw[(size_t)(n0 + rl + i*16)*HH + k0 + kl];
    }
    __syncthreads();
    #pragma unroll
    for (int kk = 0; kk < 16; kk++){
      const float4 ra = *(const float4*)&As[kk][ty*4];
      const float4 rb = *(const float4*)&Bs[kk][tx*4];
      float a_[4] = {ra.x, ra.y, ra.z, ra.w};
      float b_[4] = {rb.x, rb.y, rb.z, rb.w};
      #pragma unroll
      for (int i = 0; i < 4; i++)
        #pragma unroll
        for (int j = 0; j < 4; j++)
          acc[i][j] = fmaf(a_[i], b_[j], acc[i][j]);
    }
    __syncthreads();
  }
  #pragma unroll
  for (int i = 0; i < 4; i++){
    float4 o = {acc[i][0], acc[i][1], acc[i][2], acc[i][3]};
    *(float4*)&C[(size_t)(m0 + ty*4 + i)*DD + n0 + tx*4] = o;
  }
}

// K3: gate/prec layer1 GEMM + fused layer2 reduction via atomics.
// z1[m] += sum_q relu(hidden[m]·Wg1[q] + bg1[q]) * Wg2[q]   (cols 0..511)
// z2[m] same with p-weights (cols 512..1023)
__global__ __launch_bounds__(256) void k_gemm_gp(const float* __restrict__ A,
    const float* __restrict__ Wg1, const float* __restrict__ Wp1,
    const float* __restrict__ bg1, const float* __restrict__ bp1,
    const float* __restrict__ Wg2, const float* __restrict__ Wp2,
    float* __restrict__ z1, float* __restrict__ z2){
  __shared__ float As[16][68];
  __shared__ float Bs[16][68];
  const int tid = threadIdx.x;
  const int tx = tid & 15, ty = tid >> 4;
  const int m0 = blockIdx.x*64;
  const int cbg = blockIdx.y*64;
  const bool isP = (cbg >= HQ);
  const float* Bw = isP ? Wp1 : Wg1;
  const float* b1 = isP ? bp1 : bg1;
  const float* w2 = isP ? Wp2 : Wg2;
  float* zt = isP ? z2 : z1;
  const int cb = isP ? (cbg - HQ) : cbg;
  float acc[4][4] = {};
  const int kl = tid & 15, rl = tid >> 4;
  for (int k0 = 0; k0 < HH; k0 += 16){
    #pragma unroll
    for (int i = 0; i < 4; i++){
      As[kl][rl + i*16] = A[(size_t)(m0 + rl + i*16)*HH + k0 + kl];
      Bs[kl][rl + i*16] = Bw[(size_t)(cb + rl + i*16)*HH + k0 + kl];
    }
    __syncthreads();
    #pragma unroll
    for (int kk = 0; kk < 16; kk++){
      const float4 ra = *(const float4*)&As[kk][ty*4];
      const float4 rb = *(const float4*)&Bs[kk][tx*4];
      float a_[4] = {ra.x, ra.y, ra.z, ra.w};
      float b_[4] = {rb.x, rb.y, rb.z, rb.w};
      #pragma unroll
      for (int i = 0; i < 4; i++)
        #pragma unroll
        for (int j = 0; j < 4; j++)
          acc[i][j] = fmaf(a_[i], b_[j], acc[i][j]);
    }
    __syncthreads();
  }
  float w[4], bb[4];
  #pragma unroll
  for (int j = 0; j < 4; j++){ w[j] = w2[cb + tx*4 + j]; bb[j] = b1[cb + tx*4 + j]; }
  #pragma unroll
  for (int i = 0; i < 4; i++){
    float s = 0.f;
    #pragma unroll
    for (int j = 0; j < 4; j++){
      float v = acc[i][j] + bb[j];
      s += fmaxf(v, 0.f) * w[j];
    }
    atomicAdd(&zt[m0 + ty*4 + i], s);
  }
}

// K4: per-t finalize: prec_mean, normalize obs_mean, write obs_beliefs + meaningful,
// store obs_radii + bf16 o_angles
__global__ __launch_bounds__(256) void k_obs_fin(const float* __restrict__ obs_mean,
    const float* __restrict__ z1, const float* __restrict__ z2,
    const float* __restrict__ bg2, const float* __restrict__ bp2,
    float* __restrict__ out0, float* __restrict__ out3,
    float* __restrict__ obs_radii, unsigned short* __restrict__ obf){
  const int t = blockIdx.x, tid = threadIdx.x;
  __shared__ float red[256];
  __shared__ float pmsh;
  if (tid < TB){
    float a = z1[tid*TT + t] + bg2[0];
    float b = z2[tid*TT + t] + bp2[0];
    float gate = 1.f/(1.f + expf(-a));
    float sp = (b > 0.f) ? (b + log1pf(expf(-b))) : log1pf(expf(b));
    red[tid] = gate * sp;
  }
  __syncthreads();
  if (tid == 0) pmsh = 0.25f*(red[0]+red[1]+red[2]+red[3]);
  __syncthreads();
  const float x = obs_mean[(size_t)t*DD + tid];
  red[tid] = x*x;
  __syncthreads();
  #pragma unroll
  for (int s = 128; s > 0; s >>= 1){ if (tid < s) red[tid] += red[tid+s]; __syncthreads(); }
  const float nrm = sqrtf(red[0]);
  const float pm = pmsh;
  __syncthreads();
  const float ob = (x / fmaxf(nrm, 1e-8f)) * pm;
  out0[(size_t)t*DD + tid] = ob;
  red[tid] = ob*ob;
  __syncthreads();
  #pragma unroll
  for (int s = 128; s > 0; s >>= 1){ if (tid < s) red[tid] += red[tid+s]; __syncthreads(); }
  const float r2 = sqrtf(red[0]);
  if (tid == 0){
    obs_radii[t] = r2;
    out3[t] = (r2 > 0.05f) ? 1.f : 0.f;
  }
  const float oa = ob / fmaxf(r2, 1e-8f);
  obf[(size_t)t*DD + tid] = f2bf(oa);
}

// K5: normalize beliefs -> bf16 angles. one wave per n.
__global__ __launch_bounds__(256) void k_beliefs(const float* __restrict__ bel,
    unsigned short* __restrict__ bbf){
  const int n = (blockIdx.x*256 + threadIdx.x) >> 6;
  const int lane = threadIdx.x & 63;
  const float4 v = *(const float4*)(bel + (size_t)n*DD + lane*4);
  float s = v.x*v.x + v.y*v.y + v.z*v.z + v.w*v.w;
  #pragma unroll
  for (int m = 1; m < 64; m <<= 1) s += __shfl_xor(s, m);
  const float inv = 1.f / fmaxf(sqrtf(s), 1e-8f);
  ushort4 o;
  o.x = f2bf(v.x*inv); o.y = f2bf(v.y*inv); o.z = f2bf(v.z*inv); o.w = f2bf(v.w*inv);
  *(ushort4*)(bbf + (size_t)n*DD + lane*4) = o;
}

// K5b: any_active flag
__global__ __launch_bounds__(256) void k_any(const unsigned char* __restrict__ mask,
    int* __restrict__ flag){
  __shared__ int s;
  if (threadIdx.x == 0) s = 0;
  __syncthreads();
  int any = 0;
  for (int i = threadIdx.x; i < NN; i += 256) any |= (mask[i] != 0);
  if (any) s = 1;
  __syncthreads();
  if (threadIdx.x == 0) flag[0] = s;
}

// K6: fused sims + masked max/argmax. grid (T/64, 8 n-splits), 256 thr (4 waves).
// Each wave owns a 16-row t-tile; block stages 64-n b-tiles in LDS.
__global__ __launch_bounds__(256) void k_sims(const unsigned short* __restrict__ obf,
    const unsigned short* __restrict__ bbf, const unsigned char* __restrict__ mask,
    float* __restrict__ pmax, int* __restrict__ pidx){
  const int t0 = blockIdx.x * 64;
  const int ns = blockIdx.y;
  const int nbase0 = ns * (NN/8);
  const int tid = threadIdx.x;
  const int w = tid >> 6, lane = tid & 63;
  const int lr = lane & 15, q = lane >> 4;
  __shared__ __align__(16) unsigned short bt[64*264];
  __shared__ unsigned char am[64];
  // A fragments for this wave's 16 t-rows, K=256 -> 8 k-steps
  bf16x8 afr[8];
  {
    const unsigned short* ap = obf + (size_t)(t0 + w*16 + lr)*DD + q*8;
    #pragma unroll
    for (int ks = 0; ks < 8; ks++)
      afr[ks] = as_bf16x8(*(const uint4*)(ap + ks*32));
  }
  float vmax[4] = {-INFINITY, -INFINITY, -INFINITY, -INFINITY};
  int   vidx[4] = {-1, -1, -1, -1};
  for (int it = 0; it < (NN/8)/64; it++){
    const int nb = nbase0 + it*64;
    __syncthreads();
    {
      const unsigned short* src = bbf + (size_t)nb*DD;
      #pragma unroll
      for (int i = 0; i < 8; i++){
        int c = tid + i*256;          // 16B chunk id, 2048 total
        int row = c >> 5, c16 = c & 31;
        uint4 u = *(const uint4*)(src + row*DD + c16*8);
        *(uint4*)(bt + row*264 + c16*8) = u;
      }
      if (tid < 64) am[tid] = mask[nb + tid];
    }
    __syncthreads();
    #pragma unroll
    for (int sub = 0; sub < 4; sub++){
      f32x4 acc = {0.f, 0.f, 0.f, 0.f};
      const unsigned short* bp = bt + (sub*16 + lr)*264 + q*8;
      #pragma unroll
      for (int ks = 0; ks < 8; ks++){
        bf16x8 bfr = as_bf16x8(*(const uint4*)(bp + ks*32));
        acc = __builtin_amdgcn_mfma_f32_16x16x32_bf16(afr[ks], bfr, acc, 0, 0, 0);
      }
      if (am[sub*16 + lr]){
        const int n = nb + sub*16 + lr;
        #pragma unroll
        for (int r = 0; r < 4; r++)
          if (acc[r] > vmax[r]){ vmax[r] = acc[r]; vidx[r] = n; }
      }
    }
  }
  // reduce across the 16 columns (lanes within quad), first-index tie-break
  #pragma unroll
  for (int mk = 1; mk < 16; mk <<= 1){
    #pragma unroll
    for (int r = 0; r < 4; r++){
      float om = __shfl_xor(vmax[r], mk);
      int   oi = __shfl_xor(vidx[r], mk);
      if (om > vmax[r] || (om == vmax[r] && (unsigned)oi < (unsigned)vidx[r])){
        vmax[r] = om; vidx[r] = oi;
      }
    }
  }
  if (lr == 0){
    #pragma unroll
    for (int r = 0; r < 4; r++){
      const int t = t0 + w*16 + q*4 + r;
      pmax[ns*TT + t] = vmax[r];
      pidx[ns*TT + t] = vidx[r];
    }
  }
}

// K7: combine n-splits, apply match logic -> sims_out, slots
__global__ __launch_bounds__(256) void k_combine(const float* __restrict__ pmax,
    const int* __restrict__ pidx, const float* __restrict__ obs_radii,
    const int* __restrict__ flag, float* __restrict__ out1, float* __restrict__ out2){
  const int t = blockIdx.x*256 + threadIdx.x;
  float best = -INFINITY; int bi = -1;
  #pragma unroll
  for (int s = 0; s < 8; s++){
    float m = pmax[s*TT + t];
    if (m > best){ best = m; bi = pidx[s*TT + t]; }
  }
  const bool anyA = (flag[0] != 0);
  const bool mf = obs_radii[t] > 0.05f;
  const bool matched = mf && anyA && (best > 0.5f);
  out1[t] = matched ? best : 0.f;
  out2[t] = matched ? (float)bi : -1.f;
}

extern "C" void kernel_launch(void* const* d_in, const int* in_sizes, int n_in,
                              void* d_out, int out_size, void* d_ws, size_t ws_size,
                              hipStream_t stream) {
  const float* hidden = (const float*)d_in[0];
  const float* beliefs = (const float*)d_in[1];
  const unsigned char* amask = (const unsigned char*)d_in[2];
  const float* W_obs = (const float*)d_in[3];
  const float* W_g1 = (const float*)d_in[4];
  const float* b_g1 = (const float*)d_in[5];
  const float* W_g2 = (const float*)d_in[6];
  const float* b_g2 = (const float*)d_in[7];
  const float* W_p1 = (const float*)d_in[8];
  const float* b_p1 = (const float*)d_in[9];
  const float* W_p2 = (const float*)d_in[10];
  const float* b_p2 = (const float*)d_in[11];

  char* ws = (char*)d_ws;
  const size_t HM_OFF   = 0;                       // T*H f32       33554432
  const size_t OM_OFF   = 33554432;                // T*D f32        4194304
  const size_t Z1_OFF   = 37748736;                // M f32            65536
  const size_t Z2_OFF   = 37814272;                // M f32            65536
  const size_t RAD_OFF  = 37879808;                // T f32            16384
  const size_t FLAG_OFF = 37896192;                // int                 256
  const size_t OBF_OFF  = 37896448;                // T*D bf16        2097152
  const size_t BBF_OFF  = 39993600;                // N*D bf16       16777216
  const size_t PMAX_OFF = 56770816;                // 8*T f32          131072
  const size_t PIDX_OFF = 56901888;                // 8*T int          131072

  float* hm  = (float*)(ws + HM_OFF);
  float* om  = (float*)(ws + OM_OFF);
  float* z1  = (float*)(ws + Z1_OFF);
  float* z2  = (float*)(ws + Z2_OFF);
  float* rad = (float*)(ws + RAD_OFF);
  int*   flg = (int*)(ws + FLAG_OFF);
  unsigned short* obf = (unsigned short*)(ws + OBF_OFF);
  unsigned short* bbf = (unsigned short*)(ws + BBF_OFF);
  float* pmax = (float*)(ws + PMAX_OFF);
  int*   pidx = (int*)(ws + PIDX_OFF);

  float* out0 = (float*)d_out;            // [T,D] obs_beliefs
  float* out1 = out0 + (size_t)TT*DD;     // [T] sims_out
  float* out2 = out1 + TT;                // [T] slots
  float* out3 = out2 + TT;                // [T] meaningful

  hipMemsetAsync(ws + Z1_OFF, 0, 2*MM*sizeof(float), stream);

  k_mean_b  <<<TT*HH/4/256, 256, 0, stream>>>(hidden, hm);
  k_gemm_obs<<<dim3(TT/64, DD/64), 256, 0, stream>>>(hm, W_obs, om);
  k_gemm_gp <<<dim3(MM/64, 16), 256, 0, stream>>>(hidden, W_g1, W_p1, b_g1, b_p1,
                                                  W_g2, W_p2, z1, z2);
  k_obs_fin <<<TT, 256, 0, stream>>>(om, z1, z2, b_g2, b_p2, out0, out3, rad, obf);
  k_beliefs <<<NN/4, 256, 0, stream>>>(beliefs, bbf);
  k_any     <<<1, 256, 0, stream>>>(amask, flg);
  k_sims    <<<dim3(TT/64, 8), 256, 0, stream>>>(obf, bbf, amask, pmax, pidx);
  k_combine <<<TT/256, 256, 0, stream>>>(pmax, pidx, rad, flg, out1, out2);
}

// Round 2
// 701.640 us; speedup vs baseline: 2.2437x; 2.2437x over previous
//
#include <hip/hip_runtime.h>
#include <hip/hip_bf16.h>
#include <math.h>

#define TB 4
#define TT 4096
#define HH 2048
#define DD 256
#define NN 32768
#define HQ 512
#define MM (TB*TT)

typedef __attribute__((ext_vector_type(8))) short bf16x8;
typedef __attribute__((ext_vector_type(4))) float f32x4;

__device__ inline unsigned short f2bf(float x){
  __hip_bfloat16 h = __float2bfloat16(x);
  return *reinterpret_cast<unsigned short*>(&h);
}

__device__ inline void split_bf16(float a, unsigned short &hi, unsigned short &lo){
  __hip_bfloat16 h = __float2bfloat16(a);
  hi = *reinterpret_cast<unsigned short*>(&h);
  float hf = __bfloat162float(h);
  __hip_bfloat16 l = __float2bfloat16(a - hf);
  lo = *reinterpret_cast<unsigned short*>(&l);
}

__device__ inline bf16x8 as_bf16x8(uint4 u){ bf16x8 r; __builtin_memcpy(&r,&u,16); return r; }

// K1: batch-mean (bf16 out) + fused fp32->bf16 hi/lo split of all of hidden
__global__ __launch_bounds__(256) void k_mean_cvt(const float* __restrict__ h,
    unsigned short* __restrict__ hmb,
    unsigned short* __restrict__ Ahi, unsigned short* __restrict__ Alo){
  const size_t i = (size_t)blockIdx.x*256 + threadIdx.x;   // float4 idx in [T*H/4]
  const size_t TH4 = (size_t)TT*HH/4;
  const float4* p = (const float4*)h;
  float4 v[4];
  #pragma unroll
  for (int b = 0; b < 4; b++) v[b] = p[i + (size_t)b*TH4];
  #pragma unroll
  for (int b = 0; b < 4; b++){
    ushort4 hi4, lo4;
    split_bf16(v[b].x, hi4.x, lo4.x);
    split_bf16(v[b].y, hi4.y, lo4.y);
    split_bf16(v[b].z, hi4.z, lo4.z);
    split_bf16(v[b].w, hi4.w, lo4.w);
    *(ushort4*)(Ahi + (size_t)b*TT*HH + i*4) = hi4;
    *(ushort4*)(Alo + (size_t)b*TT*HH + i*4) = lo4;
  }
  float4 m;
  m.x = 0.25f*(v[0].x+v[1].x+v[2].x+v[3].x);
  m.y = 0.25f*(v[0].y+v[1].y+v[2].y+v[3].y);
  m.z = 0.25f*(v[0].z+v[1].z+v[2].z+v[3].z);
  m.w = 0.25f*(v[0].w+v[1].w+v[2].w+v[3].w);
  ushort4 o; o.x = f2bf(m.x); o.y = f2bf(m.y); o.z = f2bf(m.z); o.w = f2bf(m.w);
  *(ushort4*)(hmb + i*4) = o;
}

// K2: W_g1||W_p1 -> bf16 hi/lo [1024,2048]
__global__ __launch_bounds__(256) void k_cvt_w(const float* __restrict__ Wg1,
    const float* __restrict__ Wp1,
    unsigned short* __restrict__ Whi, unsigned short* __restrict__ Wlo){
  const int idx4 = blockIdx.x*256 + threadIdx.x;     // 524288 float4s
  const int n = idx4 >> 9;                           // row 0..1023
  const int c = (idx4 & 511)*4;
  const float* src = (n < HQ) ? (Wg1 + (size_t)n*HH + c) : (Wp1 + (size_t)(n-HQ)*HH + c);
  float4 v = *(const float4*)src;
  ushort4 hi4, lo4;
  split_bf16(v.x, hi4.x, lo4.x);
  split_bf16(v.y, hi4.y, lo4.y);
  split_bf16(v.z, hi4.z, lo4.z);
  split_bf16(v.w, hi4.w, lo4.w);
  *(ushort4*)(Whi + (size_t)idx4*4) = hi4;
  *(ushort4*)(Wlo + (size_t)idx4*4) = lo4;
}

// K2b: W_obs -> bf16 [256,2048]
__global__ __launch_bounds__(256) void k_cvt_wobs(const float* __restrict__ W,
    unsigned short* __restrict__ Wb){
  const int idx4 = blockIdx.x*256 + threadIdx.x;     // 131072 float4s
  float4 v = *(const float4*)(W + (size_t)idx4*4);
  ushort4 o; o.x = f2bf(v.x); o.y = f2bf(v.y); o.z = f2bf(v.z); o.w = f2bf(v.w);
  *(ushort4*)(Wb + (size_t)idx4*4) = o;
}

// K3: obs_mean = hmb @ wob^T  (bf16 MFMA, f32 out)  [4096,2048]x[256,2048]^T
__global__ __launch_bounds__(256) void k_obs(const unsigned short* __restrict__ A,
    const unsigned short* __restrict__ Bw, float* __restrict__ C){
  const int n0 = blockIdx.x*128, m0 = blockIdx.y*128;
  const int tid = threadIdx.x;
  const int w = tid>>6, lane = tid&63, lr = lane&15, q = lane>>4;
  __shared__ __align__(16) unsigned short Bs[128][40];
  f32x4 acc[2][8] = {};
  for (int k0 = 0; k0 < HH; k0 += 32){
    __syncthreads();
    #pragma unroll
    for (int ii = 0; ii < 2; ii++){
      int idx = tid + ii*256;
      int row = idx >> 2, c8 = (idx & 3)*8;
      *(uint4*)&Bs[row][c8] = *(const uint4*)(Bw + (size_t)(n0+row)*HH + k0 + c8);
    }
    bf16x8 a[2];
    #pragma unroll
    for (int i = 0; i < 2; i++)
      a[i] = as_bf16x8(*(const uint4*)(A + (size_t)(m0 + w*32 + i*16 + lr)*HH + k0 + q*8));
    __syncthreads();
    #pragma unroll
    for (int j = 0; j < 8; j++){
      bf16x8 b = as_bf16x8(*(const uint4*)&Bs[j*16 + lr][q*8]);
      #pragma unroll
      for (int i = 0; i < 2; i++)
        acc[i][j] = __builtin_amdgcn_mfma_f32_16x16x32_bf16(a[i], b, acc[i][j], 0, 0, 0);
    }
  }
  #pragma unroll
  for (int i = 0; i < 2; i++)
    #pragma unroll
    for (int j = 0; j < 8; j++)
      #pragma unroll
      for (int r = 0; r < 4; r++)
        C[(size_t)(m0 + w*32 + i*16 + q*4 + r)*DD + n0 + j*16 + lr] = acc[i][j][r];
}

// K4: gate/prec layer1 via split-bf16 3-product MFMA + fused relu*w2 reduction
__global__ __launch_bounds__(256) void k_gp(const unsigned short* __restrict__ Ahi,
    const unsigned short* __restrict__ Alo,
    const unsigned short* __restrict__ Whi, const unsigned short* __restrict__ Wlo,
    const float* __restrict__ bg1, const float* __restrict__ bp1,
    const float* __restrict__ Wg2, const float* __restrict__ Wp2,
    float* __restrict__ z1, float* __restrict__ z2){
  const int n0 = blockIdx.x*128;     // col block in [0,1024)
  const int m0 = blockIdx.y*128;
  const int tid = threadIdx.x;
  const int w = tid>>6, lane = tid&63, lr = lane&15, q = lane>>4;
  __shared__ __align__(16) unsigned short Bhi[128][40];
  __shared__ __align__(16) unsigned short Blo[128][40];
  f32x4 acc[2][8] = {};
  for (int k0 = 0; k0 < HH; k0 += 32){
    __syncthreads();
    #pragma unroll
    for (int ii = 0; ii < 2; ii++){
      int idx = tid + ii*256;
      int row = idx >> 2, c8 = (idx & 3)*8;
      const size_t g = (size_t)(n0+row)*HH + k0 + c8;
      *(uint4*)&Bhi[row][c8] = *(const uint4*)(Whi + g);
      *(uint4*)&Blo[row][c8] = *(const uint4*)(Wlo + g);
    }
    bf16x8 ah[2], al[2];
    #pragma unroll
    for (int i = 0; i < 2; i++){
      const size_t g = (size_t)(m0 + w*32 + i*16 + lr)*HH + k0 + q*8;
      ah[i] = as_bf16x8(*(const uint4*)(Ahi + g));
      al[i] = as_bf16x8(*(const uint4*)(Alo + g));
    }
    __syncthreads();
    #pragma unroll
    for (int j = 0; j < 8; j++){
      bf16x8 bh = as_bf16x8(*(const uint4*)&Bhi[j*16 + lr][q*8]);
      bf16x8 bl = as_bf16x8(*(const uint4*)&Blo[j*16 + lr][q*8]);
      #pragma unroll
      for (int i = 0; i < 2; i++){
        acc[i][j] = __builtin_amdgcn_mfma_f32_16x16x32_bf16(ah[i], bh, acc[i][j], 0, 0, 0);
        acc[i][j] = __builtin_amdgcn_mfma_f32_16x16x32_bf16(al[i], bh, acc[i][j], 0, 0, 0);
        acc[i][j] = __builtin_amdgcn_mfma_f32_16x16x32_bf16(ah[i], bl, acc[i][j], 0, 0, 0);
      }
    }
  }
  // epilogue: z[m] += sum_n relu(C[m,n] + b1[n]) * w2[n]
  const bool isP = (n0 >= HQ);
  const float* b1 = isP ? bp1 : bg1;
  const float* w2 = isP ? Wp2 : Wg2;
  float* zt = isP ? z2 : z1;
  const int nb = n0 - (isP ? HQ : 0);
  float bv[8], wv[8];
  #pragma unroll
  for (int j = 0; j < 8; j++){
    int n = nb + j*16 + lr;
    bv[j] = b1[n]; wv[j] = w2[n];
  }
  #pragma unroll
  for (int i = 0; i < 2; i++){
    float s[4];
    #pragma unroll
    for (int r = 0; r < 4; r++){
      float t = 0.f;
      #pragma unroll
      for (int j = 0; j < 8; j++)
        t += fmaxf(acc[i][j][r] + bv[j], 0.f) * wv[j];
      s[r] = t;
    }
    #pragma unroll
    for (int mk = 1; mk < 16; mk <<= 1)
      #pragma unroll
      for (int r = 0; r < 4; r++)
        s[r] += __shfl_xor(s[r], mk);
    if (lr == 0){
      #pragma unroll
      for (int r = 0; r < 4; r++)
        atomicAdd(&zt[m0 + w*32 + i*16 + q*4 + r], s[r]);
    }
  }
}

// K5: per-t finalize
__global__ __launch_bounds__(256) void k_obs_fin(const float* __restrict__ obs_mean,
    const float* __restrict__ z1, const float* __restrict__ z2,
    const float* __restrict__ bg2, const float* __restrict__ bp2,
    float* __restrict__ out0, float* __restrict__ out3,
    float* __restrict__ obs_radii, unsigned short* __restrict__ obf){
  const int t = blockIdx.x, tid = threadIdx.x;
  __shared__ float red[256];
  __shared__ float pmsh;
  if (tid < TB){
    float a = z1[tid*TT + t] + bg2[0];
    float b = z2[tid*TT + t] + bp2[0];
    float gate = 1.f/(1.f + expf(-a));
    float sp = (b > 0.f) ? (b + log1pf(expf(-b))) : log1pf(expf(b));
    red[tid] = gate * sp;
  }
  __syncthreads();
  if (tid == 0) pmsh = 0.25f*(red[0]+red[1]+red[2]+red[3]);
  __syncthreads();
  const float x = obs_mean[(size_t)t*DD + tid];
  red[tid] = x*x;
  __syncthreads();
  #pragma unroll
  for (int s = 128; s > 0; s >>= 1){ if (tid < s) red[tid] += red[tid+s]; __syncthreads(); }
  const float nrm = sqrtf(red[0]);
  const float pm = pmsh;
  __syncthreads();
  const float ob = (x / fmaxf(nrm, 1e-8f)) * pm;
  out0[(size_t)t*DD + tid] = ob;
  red[tid] = ob*ob;
  __syncthreads();
  #pragma unroll
  for (int s = 128; s > 0; s >>= 1){ if (tid < s) red[tid] += red[tid+s]; __syncthreads(); }
  const float r2 = sqrtf(red[0]);
  if (tid == 0){
    obs_radii[t] = r2;
    out3[t] = (r2 > 0.05f) ? 1.f : 0.f;
  }
  const float oa = ob / fmaxf(r2, 1e-8f);
  obf[(size_t)t*DD + tid] = f2bf(oa);
}

// K6: normalize beliefs -> bf16 angles
__global__ __launch_bounds__(256) void k_beliefs(const float* __restrict__ bel,
    unsigned short* __restrict__ bbf){
  const int n = (blockIdx.x*256 + threadIdx.x) >> 6;
  const int lane = threadIdx.x & 63;
  const float4 v = *(const float4*)(bel + (size_t)n*DD + lane*4);
  float s = v.x*v.x + v.y*v.y + v.z*v.z + v.w*v.w;
  #pragma unroll
  for (int m = 1; m < 64; m <<= 1) s += __shfl_xor(s, m);
  const float inv = 1.f / fmaxf(sqrtf(s), 1e-8f);
  ushort4 o;
  o.x = f2bf(v.x*inv); o.y = f2bf(v.y*inv); o.z = f2bf(v.z*inv); o.w = f2bf(v.w*inv);
  *(ushort4*)(bbf + (size_t)n*DD + lane*4) = o;
}

// K6b: any_active flag
__global__ __launch_bounds__(256) void k_any(const unsigned char* __restrict__ mask,
    int* __restrict__ flag){
  __shared__ int s;
  if (threadIdx.x == 0) s = 0;
  __syncthreads();
  int any = 0;
  for (int i = threadIdx.x; i < NN; i += 256) any |= (mask[i] != 0);
  if (any) s = 1;
  __syncthreads();
  if (threadIdx.x == 0) flag[0] = s;
}

// K7: fused sims + masked max/argmax
__global__ __launch_bounds__(256) void k_sims(const unsigned short* __restrict__ obf,
    const unsigned short* __restrict__ bbf, const unsigned char* __restrict__ mask,
    float* __restrict__ pmax, int* __restrict__ pidx){
  const int t0 = blockIdx.x * 64;
  const int ns = blockIdx.y;
  const int nbase0 = ns * (NN/8);
  const int tid = threadIdx.x;
  const int w = tid >> 6, lane = tid & 63;
  const int lr = lane & 15, q = lane >> 4;
  __shared__ __align__(16) unsigned short bt[64*264];
  __shared__ unsigned char am[64];
  bf16x8 afr[8];
  {
    const unsigned short* ap = obf + (size_t)(t0 + w*16 + lr)*DD + q*8;
    #pragma unroll
    for (int ks = 0; ks < 8; ks++)
      afr[ks] = as_bf16x8(*(const uint4*)(ap + ks*32));
  }
  float vmax[4] = {-INFINITY, -INFINITY, -INFINITY, -INFINITY};
  int   vidx[4] = {-1, -1, -1, -1};
  for (int it = 0; it < (NN/8)/64; it++){
    const int nb = nbase0 + it*64;
    __syncthreads();
    {
      const unsigned short* src = bbf + (size_t)nb*DD;
      #pragma unroll
      for (int i = 0; i < 8; i++){
        int c = tid + i*256;
        int row = c >> 5, c16 = c & 31;
        uint4 u = *(const uint4*)(src + row*DD + c16*8);
        *(uint4*)(bt + row*264 + c16*8) = u;
      }
      if (tid < 64) am[tid] = mask[nb + tid];
    }
    __syncthreads();
    #pragma unroll
    for (int sub = 0; sub < 4; sub++){
      f32x4 acc = {0.f, 0.f, 0.f, 0.f};
      const unsigned short* bp = bt + (sub*16 + lr)*264 + q*8;
      #pragma unroll
      for (int ks = 0; ks < 8; ks++){
        bf16x8 bfr = as_bf16x8(*(const uint4*)(bp + ks*32));
        acc = __builtin_amdgcn_mfma_f32_16x16x32_bf16(afr[ks], bfr, acc, 0, 0, 0);
      }
      if (am[sub*16 + lr]){
        const int n = nb + sub*16 + lr;
        #pragma unroll
        for (int r = 0; r < 4; r++)
          if (acc[r] > vmax[r]){ vmax[r] = acc[r]; vidx[r] = n; }
      }
    }
  }
  #pragma unroll
  for (int mk = 1; mk < 16; mk <<= 1){
    #pragma unroll
    for (int r = 0; r < 4; r++){
      float om = __shfl_xor(vmax[r], mk);
      int   oi = __shfl_xor(vidx[r], mk);
      if (om > vmax[r] || (om == vmax[r] && (unsigned)oi < (unsigned)vidx[r])){
        vmax[r] = om; vidx[r] = oi;
      }
    }
  }
  if (lr == 0){
    #pragma unroll
    for (int r = 0; r < 4; r++){
      const int t = t0 + w*16 + q*4 + r;
      pmax[ns*TT + t] = vmax[r];
      pidx[ns*TT + t] = vidx[r];
    }
  }
}

// K8: combine n-splits + match logic
__global__ __launch_bounds__(256) void k_combine(const float* __restrict__ pmax,
    const int* __restrict__ pidx, const float* __restrict__ obs_radii,
    const int* __restrict__ flag, float* __restrict__ out1, float* __restrict__ out2){
  const int t = blockIdx.x*256 + threadIdx.x;
  float best = -INFINITY; int bi = -1;
  #pragma unroll
  for (int s = 0; s < 8; s++){
    float m = pmax[s*TT + t];
    if (m > best){ best = m; bi = pidx[s*TT + t]; }
  }
  const bool anyA = (flag[0] != 0);
  const bool mf = obs_radii[t] > 0.05f;
  const bool matched = mf && anyA && (best > 0.5f);
  out1[t] = matched ? best : 0.f;
  out2[t] = matched ? (float)bi : -1.f;
}

extern "C" void kernel_launch(void* const* d_in, const int* in_sizes, int n_in,
                              void* d_out, int out_size, void* d_ws, size_t ws_size,
                              hipStream_t stream) {
  const float* hidden = (const float*)d_in[0];
  const float* beliefs = (const float*)d_in[1];
  const unsigned char* amask = (const unsigned char*)d_in[2];
  const float* W_obs = (const float*)d_in[3];
  const float* W_g1 = (const float*)d_in[4];
  const float* b_g1 = (const float*)d_in[5];
  const float* W_g2 = (const float*)d_in[6];
  const float* b_g2 = (const float*)d_in[7];
  const float* W_p1 = (const float*)d_in[8];
  const float* b_p1 = (const float*)d_in[9];
  const float* W_p2 = (const float*)d_in[10];
  const float* b_p2 = (const float*)d_in[11];

  char* ws = (char*)d_ws;
  const size_t AHI_OFF  = 0;                 // 16384*2048*2 = 67108864
  const size_t ALO_OFF  = 67108864;          // 67108864
  const size_t HMB_OFF  = 134217728;         // 4096*2048*2 = 16777216
  const size_t WHI_OFF  = 150994944;         // 1024*2048*2 = 4194304
  const size_t WLO_OFF  = 155189248;         // 4194304
  const size_t WOB_OFF  = 159383552;         // 256*2048*2 = 1048576
  const size_t OM_OFF   = 160432128;         // 4096*256*4 = 4194304
  const size_t Z1_OFF   = 164626432;         // 65536
  const size_t Z2_OFF   = 164691968;         // 65536
  const size_t RAD_OFF  = 164757504;         // 16384
  const size_t FLAG_OFF = 164773888;         // 256
  const size_t OBF_OFF  = 164774144;         // 2097152
  const size_t BBF_OFF  = 166871296;         // 16777216
  const size_t PMAX_OFF = 183648512;         // 131072
  const size_t PIDX_OFF = 183779584;         // 131072   end ~183.9MB

  unsigned short* Ahi = (unsigned short*)(ws + AHI_OFF);
  unsigned short* Alo = (unsigned short*)(ws + ALO_OFF);
  unsigned short* hmb = (unsigned short*)(ws + HMB_OFF);
  unsigned short* Whi = (unsigned short*)(ws + WHI_OFF);
  unsigned short* Wlo = (unsigned short*)(ws + WLO_OFF);
  unsigned short* wob = (unsigned short*)(ws + WOB_OFF);
  float* om  = (float*)(ws + OM_OFF);
  float* z1  = (float*)(ws + Z1_OFF);
  float* z2  = (float*)(ws + Z2_OFF);
  float* rad = (float*)(ws + RAD_OFF);
  int*   flg = (int*)(ws + FLAG_OFF);
  unsigned short* obf = (unsigned short*)(ws + OBF_OFF);
  unsigned short* bbf = (unsigned short*)(ws + BBF_OFF);
  float* pmax = (float*)(ws + PMAX_OFF);
  int*   pidx = (int*)(ws + PIDX_OFF);

  float* out0 = (float*)d_out;            // [T,D] obs_beliefs
  float* out1 = out0 + (size_t)TT*DD;     // [T] sims_out
  float* out2 = out1 + TT;                // [T] slots
  float* out3 = out2 + TT;                // [T] meaningful

  hipMemsetAsync(ws + Z1_OFF, 0, 2*MM*sizeof(float), stream);

  k_mean_cvt<<<TT*HH/4/256, 256, 0, stream>>>(hidden, hmb, Ahi, Alo);
  k_cvt_w   <<<(1024*HH/4)/256, 256, 0, stream>>>(W_g1, W_p1, Whi, Wlo);
  k_cvt_wobs<<<(DD*HH/4)/256, 256, 0, stream>>>(W_obs, wob);
  k_obs     <<<dim3(DD/128, TT/128), 256, 0, stream>>>(hmb, wob, om);
  k_gp      <<<dim3(8, MM/128), 256, 0, stream>>>(Ahi, Alo, Whi, Wlo, b_g1, b_p1,
                                                  W_g2, W_p2, z1, z2);
  k_obs_fin <<<TT, 256, 0, stream>>>(om, z1, z2, b_g2, b_p2, out0, out3, rad, obf);
  k_beliefs <<<NN/4, 256, 0, stream>>>(beliefs, bbf);
  k_any     <<<1, 256, 0, stream>>>(amask, flg);
  k_sims    <<<dim3(TT/64, 8), 256, 0, stream>>>(obf, bbf, amask, pmax, pidx);
  k_combine <<<TT/256, 256, 0, stream>>>(pmax, pidx, rad, flg, out1, out2);
}